// Round 5
// baseline (405.194 us; speedup 1.0000x reference)
//
#include <hip/hip_runtime.h>

#define Bc 16
#define Sc 512
#define Dc 1024
#define Hc 16
#define DHc 64

#define AS1 __attribute__((address_space(1)))
#define AS3 __attribute__((address_space(3)))

typedef __attribute__((ext_vector_type(8))) __bf16 bf16x8;
typedef __attribute__((ext_vector_type(4))) float f32x4;
typedef __attribute__((ext_vector_type(8))) unsigned short ushort8;

static __device__ __forceinline__ unsigned short f2bf(float f) {
  unsigned int u = __builtin_bit_cast(unsigned int, f);
  unsigned int r = (u + 0x7fffu + ((u >> 16) & 1u)) >> 16;  // RNE
  return (unsigned short)r;
}
static __device__ __forceinline__ float bf2f(unsigned short u) {
  unsigned int x = ((unsigned int)u) << 16;
  return __builtin_bit_cast(float, x);
}

// ---------------------------------------------------------------------------
// h_bf16 = bf16( hidden + (W_in*padmask)[in_degree] + (W_out*padmask)[out_degree] )
// ---------------------------------------------------------------------------
__global__ __launch_bounds__(256) void k_pos_add(
    const float* __restrict__ hidden, const int* __restrict__ ind,
    const int* __restrict__ outd, const float* __restrict__ Win,
    const float* __restrict__ Wout, unsigned short* __restrict__ hbf) {
  int row = blockIdx.x;
  int t = threadIdx.x;
  int id = ind[row], od = outd[row];
  float fi = (id != 0) ? 1.f : 0.f;
  float fo = (od != 0) ? 1.f : 0.f;
  float4 a = ((const float4*)(hidden + (size_t)row * Dc))[t];
  float4 x = ((const float4*)(Win + (size_t)id * Dc))[t];
  float4 y = ((const float4*)(Wout + (size_t)od * Dc))[t];
  ushort4 r;
  r.x = f2bf(a.x + fi * x.x + fo * y.x);
  r.y = f2bf(a.y + fi * x.y + fo * y.y);
  r.z = f2bf(a.z + fi * x.z + fo * y.z);
  r.w = f2bf(a.w + fi * x.w + fo * y.w);
  ((ushort4*)(hbf + (size_t)row * Dc))[t] = r;
}

// ---------------------------------------------------------------------------
// Wt[n][k] = bf16(W[k][n]) for q,k,v
// ---------------------------------------------------------------------------
__global__ __launch_bounds__(256) void k_wt(
    const float* __restrict__ Wq, const float* __restrict__ Wk,
    const float* __restrict__ Wv, unsigned short* __restrict__ Wtq,
    unsigned short* __restrict__ Wtk, unsigned short* __restrict__ Wtv) {
  const float* W = blockIdx.z == 0 ? Wq : blockIdx.z == 1 ? Wk : Wv;
  unsigned short* Wt = blockIdx.z == 0 ? Wtq : blockIdx.z == 1 ? Wtk : Wtv;
  __shared__ float tile[64][65];
  int k0 = blockIdx.y * 64, n0 = blockIdx.x * 64;
  int r = threadIdx.x >> 4, c4 = (threadIdx.x & 15) * 4;
  for (int rr = r; rr < 64; rr += 16) {
    float4 v = *(const float4*)(W + (size_t)(k0 + rr) * Dc + n0 + c4);
    tile[rr][c4 + 0] = v.x;
    tile[rr][c4 + 1] = v.y;
    tile[rr][c4 + 2] = v.z;
    tile[rr][c4 + 3] = v.w;
  }
  __syncthreads();
  for (int rr = r; rr < 64; rr += 16) {
    ushort4 o;
    o.x = f2bf(tile[c4 + 0][rr]);
    o.y = f2bf(tile[c4 + 1][rr]);
    o.z = f2bf(tile[c4 + 2][rr]);
    o.w = f2bf(tile[c4 + 3][rr]);
    *(ushort4*)(Wt + (size_t)(n0 + rr) * Dc + k0 + c4) = o;
  }
}

// ---------------------------------------------------------------------------
// QKV projections, bf16 MFMA. Q,K: row-major [b,s,1024].
// V: written pre-transposed Vt[(b*16+h), dh, s] for conflict-free attn staging.
// ---------------------------------------------------------------------------
__global__ __launch_bounds__(256) void k_gemm_mfma(
    const unsigned short* __restrict__ hbf,
    const unsigned short* __restrict__ Wtq, const float* __restrict__ bq,
    const unsigned short* __restrict__ Wtk, const float* __restrict__ bk,
    const unsigned short* __restrict__ Wtv, const float* __restrict__ bv,
    unsigned short* __restrict__ Qo, unsigned short* __restrict__ Ko,
    unsigned short* __restrict__ Vt) {
  int zsel = blockIdx.z;
  const unsigned short* Wt;
  const float* bias;
  if (zsel == 0) { Wt = Wtq; bias = bq; }
  else if (zsel == 1) { Wt = Wtk; bias = bk; }
  else { Wt = Wtv; bias = bv; }

  __shared__ __align__(16) unsigned short As[128 * 32];
  __shared__ __align__(16) unsigned short Bs[128 * 32];

  int tid = threadIdx.x, lane = tid & 63, wave = tid >> 6;
  int m0 = blockIdx.y * 128, n0 = blockIdx.x * 128;
  int wr = wave >> 1, wc = wave & 1;

  f32x4 acc[4][4] = {};

  int srow = lane >> 2;
  int skb = (lane & 3) * 8;
  const unsigned short* gA = hbf + (size_t)(m0 + srow) * Dc + skb;
  const unsigned short* gB = Wt + (size_t)(n0 + srow) * Dc + skb;

  int fr = lane & 15, kg = (lane >> 4) * 8;

  for (int k0 = 0; k0 < Dc; k0 += 32) {
#pragma unroll
    for (int cc = 0; cc < 2; ++cc) {
      int c = wave + cc * 4;
      __builtin_amdgcn_global_load_lds(
          (const AS1 void*)(gA + (size_t)c * 16 * Dc + k0),
          (AS3 void*)(As + c * 16 * 32), 16, 0, 0);
      __builtin_amdgcn_global_load_lds(
          (const AS1 void*)(gB + (size_t)c * 16 * Dc + k0),
          (AS3 void*)(Bs + c * 16 * 32), 16, 0, 0);
    }
    __syncthreads();

    bf16x8 af[4], bfr[4];
#pragma unroll
    for (int m = 0; m < 4; ++m)
      af[m] = *(const bf16x8*)(As + (wr * 64 + m * 16 + fr) * 32 + kg);
#pragma unroll
    for (int n = 0; n < 4; ++n)
      bfr[n] = *(const bf16x8*)(Bs + (wc * 64 + n * 16 + fr) * 32 + kg);
#pragma unroll
    for (int m = 0; m < 4; ++m)
#pragma unroll
      for (int n = 0; n < 4; ++n)
        acc[m][n] = __builtin_amdgcn_mfma_f32_16x16x32_bf16(af[m], bfr[n], acc[m][n], 0, 0, 0);
    __syncthreads();
  }

  int fq = lane >> 4;
  if (zsel < 2) {
    unsigned short* C = (zsel == 0) ? Qo : Ko;
#pragma unroll
    for (int m = 0; m < 4; ++m) {
#pragma unroll
      for (int n = 0; n < 4; ++n) {
        int col = n0 + wc * 64 + n * 16 + fr;
        float bb = bias[col];
#pragma unroll
        for (int r = 0; r < 4; ++r) {
          int row = m0 + wr * 64 + m * 16 + fq * 4 + r;
          C[(size_t)row * Dc + col] = f2bf(acc[m][n][r] + bb);
        }
      }
    }
  } else {
    // V: pack 4 consecutive s into one 8B store at Vt[(b,h),dh,s]
#pragma unroll
    for (int m = 0; m < 4; ++m) {
#pragma unroll
      for (int n = 0; n < 4; ++n) {
        int col = n0 + wc * 64 + n * 16 + fr;  // global out-feature
        int hh = col >> 6, dh = col & 63;
        float bb = bias[col];
        int row = m0 + wr * 64 + m * 16 + fq * 4;  // 4 consecutive s
        int bb_ = row >> 9, ss = row & 511;
        ushort4 pk;
        pk.x = f2bf(acc[m][n][0] + bb);
        pk.y = f2bf(acc[m][n][1] + bb);
        pk.z = f2bf(acc[m][n][2] + bb);
        pk.w = f2bf(acc[m][n][3] + bb);
        *(ushort4*)(Vt + ((size_t)(bb_ * Hc + hh) * DHc + dh) * Sc + ss) = pk;
      }
    }
  }
}

// ---------------------------------------------------------------------------
// Fused attention: block = (b, h, 32 q-rows); 4 waves; 43648 B LDS -> 3/CU.
// S stored bf16 with XOR-granule swizzle; K/V^T staged via global_load_lds
// with swizzled per-lane global source (linear LDS dest).
// ---------------------------------------------------------------------------
#define SWB 520  // S row stride in bf16 (1040 B, 16B-aligned, 65 granules)
__global__ __launch_bounds__(256) void k_attn(
    const unsigned short* __restrict__ Qb, const unsigned short* __restrict__ Kb,
    const unsigned short* __restrict__ Vt, const int* __restrict__ spe,
    const float* __restrict__ Wspe, const float* __restrict__ mask,
    float* __restrict__ probs, float* __restrict__ ctx) {
  extern __shared__ char smem[];
  unsigned short* S = (unsigned short*)smem;              // 32*520*2 = 33280
  unsigned short* KVt = (unsigned short*)(smem + 33280);  // 64*64*2 = 8192
  float* Wb = (float*)(smem + 41472);                     // 2048
  float* Rinv = (float*)(smem + 43520);                   // 128

  int tid = threadIdx.x, lane = tid & 63, w = tid >> 6;
  int fr = lane & 15, fq = lane >> 4, kg8 = fq * 8;
  int qh = w & 1, wh = w >> 1;

  int flat = blockIdx.x;
  int swz = (flat & 7) * 512 + (flat >> 3);
  int qt = swz & 15, h = (swz >> 4) & 15, b = swz >> 8;
  int q0 = qt * 32;

  for (int i = tid; i < 512; i += 256) Wb[i] = Wspe[i * Hc + h];

  // Q fragments in registers for the whole QK^T phase
  const unsigned short* qbase = Qb + (size_t)(b * Sc + q0) * Dc + h * DHc;
  bf16x8 af[2];
#pragma unroll
  for (int kk = 0; kk < 2; ++kk)
    af[kk] = *(const bf16x8*)(qbase + (size_t)(qh * 16 + fr) * Dc + kk * 32 + kg8);

  // staging lane constants (dest is wave-uniform; source carries the swizzle)
  int l8 = lane & 7;
  int rsub = lane >> 3;
  const unsigned short* kbase = Kb + (size_t)(b * Sc) * Dc + h * DHc;
  const unsigned short* vtbase = Vt + (size_t)(b * Hc + h) * DHc * Sc;

  // ---- QK^T ----
  for (int it = 0; it < 8; ++it) {
#pragma unroll
    for (int c = 0; c < 2; ++c) {
      int rowT = w * 16 + c * 8 + rsub;
      int gsw = l8 ^ (rowT & 7);
      __builtin_amdgcn_global_load_lds(
          (const AS1 void*)(kbase + (size_t)(it * 64 + rowT) * Dc + gsw * 8),
          (AS3 void*)(KVt + (w * 16 + c * 8) * 64), 16, 0, 0);
    }
    __syncthreads();
#pragma unroll
    for (int nf = 0; nf < 2; ++nf) {
      f32x4 acc = {};
#pragma unroll
      for (int kk = 0; kk < 2; ++kk) {
        int brow = wh * 32 + nf * 16 + fr;
        bf16x8 bfrag = *(const bf16x8*)(KVt + brow * 64 + ((kk * 4 + fq) ^ (brow & 7)) * 8);
        acc = __builtin_amdgcn_mfma_f32_16x16x32_bf16(af[kk], bfrag, acc, 0, 0, 0);
      }
#pragma unroll
      for (int r = 0; r < 4; ++r) {
        int row = qh * 16 + fq * 4 + r;
        int colg = it * 8 + wh * 4 + nf * 2 + (fr >> 3);
        S[row * SWB + ((colg ^ (row & 7)) << 3) + (fr & 7)] = f2bf(acc[r] * 0.125f);
      }
    }
    __syncthreads();
  }

  // ---- softmax: 8 lanes/row, 64 cols each; bias recomputed in both passes ----
  int srow = tid >> 3, chunk = tid & 7;
  int rx = srow & 7;
  const int* spp = spe + (size_t)(b * Sc + q0 + srow) * Sc + chunk * 64;
  const float* mkp = mask + b * Sc + chunk * 64;
  unsigned short* srp = S + srow * SWB;
  float mx = -3.4e38f;
#pragma unroll
  for (int j = 0; j < 8; ++j) {
    int colg = chunk * 8 + j;
    ushort8 sv = *(const ushort8*)(srp + ((colg ^ rx) << 3));
    int4 s0 = *(const int4*)(spp + j * 8);
    int4 s1 = *(const int4*)(spp + j * 8 + 4);
    float4 k0 = *(const float4*)(mkp + j * 8);
    float4 k1 = *(const float4*)(mkp + j * 8 + 4);
    float v0 = bf2f(sv[0]) + Wb[s0.x] + k0.x;
    float v1 = bf2f(sv[1]) + Wb[s0.y] + k0.y;
    float v2 = bf2f(sv[2]) + Wb[s0.z] + k0.z;
    float v3 = bf2f(sv[3]) + Wb[s0.w] + k0.w;
    float v4 = bf2f(sv[4]) + Wb[s1.x] + k1.x;
    float v5 = bf2f(sv[5]) + Wb[s1.y] + k1.y;
    float v6 = bf2f(sv[6]) + Wb[s1.z] + k1.z;
    float v7 = bf2f(sv[7]) + Wb[s1.w] + k1.w;
    mx = fmaxf(mx, fmaxf(fmaxf(fmaxf(v0, v1), fmaxf(v2, v3)),
                         fmaxf(fmaxf(v4, v5), fmaxf(v6, v7))));
  }
  mx = fmaxf(mx, __shfl_xor(mx, 1));
  mx = fmaxf(mx, __shfl_xor(mx, 2));
  mx = fmaxf(mx, __shfl_xor(mx, 4));
  float sum = 0.f;
#pragma unroll
  for (int j = 0; j < 8; ++j) {
    int colg = chunk * 8 + j;
    ushort8 sv = *(const ushort8*)(srp + ((colg ^ rx) << 3));
    int4 s0 = *(const int4*)(spp + j * 8);
    int4 s1 = *(const int4*)(spp + j * 8 + 4);
    float4 k0 = *(const float4*)(mkp + j * 8);
    float4 k1 = *(const float4*)(mkp + j * 8 + 4);
    float e0 = __expf(bf2f(sv[0]) + Wb[s0.x] + k0.x - mx);
    float e1 = __expf(bf2f(sv[1]) + Wb[s0.y] + k0.y - mx);
    float e2 = __expf(bf2f(sv[2]) + Wb[s0.z] + k0.z - mx);
    float e3 = __expf(bf2f(sv[3]) + Wb[s0.w] + k0.w - mx);
    float e4 = __expf(bf2f(sv[4]) + Wb[s1.x] + k1.x - mx);
    float e5 = __expf(bf2f(sv[5]) + Wb[s1.y] + k1.y - mx);
    float e6 = __expf(bf2f(sv[6]) + Wb[s1.z] + k1.z - mx);
    float e7 = __expf(bf2f(sv[7]) + Wb[s1.w] + k1.w - mx);
    sum += e0 + e1 + e2 + e3 + e4 + e5 + e6 + e7;
    ushort8 ev;
    ev[0] = f2bf(e0); ev[1] = f2bf(e1); ev[2] = f2bf(e2); ev[3] = f2bf(e3);
    ev[4] = f2bf(e4); ev[5] = f2bf(e5); ev[6] = f2bf(e6); ev[7] = f2bf(e7);
    *(ushort8*)(srp + ((colg ^ rx) << 3)) = ev;
  }
  sum += __shfl_xor(sum, 1);
  sum += __shfl_xor(sum, 2);
  sum += __shfl_xor(sum, 4);
  if ((tid & 7) == 0) Rinv[srow] = 1.f / sum;
  __syncthreads();

  // ---- PV: stage V^T tiles (linear dest, swizzled source), MFMA on bf16 S ----
  f32x4 pacc[2] = {};
  for (int it = 0; it < 8; ++it) {
#pragma unroll
    for (int c = 0; c < 2; ++c) {
      int rowT = w * 16 + c * 8 + rsub;  // dh row
      int gsw = l8 ^ (rowT & 7);
      __builtin_amdgcn_global_load_lds(
          (const AS1 void*)(vtbase + (size_t)rowT * Sc + it * 64 + gsw * 8),
          (AS3 void*)(KVt + (w * 16 + c * 8) * 64), 16, 0, 0);
    }
    __syncthreads();
    int arow = qh * 16 + fr;
#pragma unroll
    for (int kk = 0; kk < 2; ++kk) {
      bf16x8 afr = *(const bf16x8*)(S + arow * SWB + (((it * 8 + kk * 4 + fq) ^ (arow & 7)) << 3));
#pragma unroll
      for (int nf = 0; nf < 2; ++nf) {
        int brow = wh * 32 + nf * 16 + fr;
        bf16x8 bfrag = *(const bf16x8*)(KVt + brow * 64 + ((kk * 4 + fq) ^ (brow & 7)) * 8);
        pacc[nf] = __builtin_amdgcn_mfma_f32_16x16x32_bf16(afr, bfrag, pacc[nf], 0, 0, 0);
      }
    }
    __syncthreads();
  }

  // ---- ctx epilogue ----
  float* cbase = ctx + (size_t)(b * Sc + q0 + qh * 16) * Dc + h * DHc + wh * 32;
#pragma unroll
  for (int nf = 0; nf < 2; ++nf)
#pragma unroll
    for (int r = 0; r < 4; ++r) {
      int row = fq * 4 + r;
      cbase[(size_t)row * Dc + nf * 16 + fr] = pacc[nf][r] * Rinv[qh * 16 + row];
    }

  // ---- probs tail: contiguous 2KB bursts per 64-lane group ----
  float* pbase = probs + (size_t)((b * Hc + h) * Sc + q0) * Sc;
  for (int t8 = 0; t8 < 8; ++t8) {
    int idx = t8 * 256 + tid;
    int row = idx >> 6, colg = idx & 63;
    ushort8 sv = *(const ushort8*)(S + row * SWB + ((colg ^ (row & 7)) << 3));
    float rv = Rinv[row];
    float4 o0, o1;
    o0.x = bf2f(sv[0]) * rv; o0.y = bf2f(sv[1]) * rv;
    o0.z = bf2f(sv[2]) * rv; o0.w = bf2f(sv[3]) * rv;
    o1.x = bf2f(sv[4]) * rv; o1.y = bf2f(sv[5]) * rv;
    o1.z = bf2f(sv[6]) * rv; o1.w = bf2f(sv[7]) * rv;
    *(float4*)(pbase + (size_t)row * Sc + colg * 8) = o0;
    *(float4*)(pbase + (size_t)row * Sc + colg * 8 + 4) = o1;
  }
}

extern "C" void kernel_launch(void* const* d_in, const int* in_sizes, int n_in,
                              void* d_out, int out_size, void* d_ws, size_t ws_size,
                              hipStream_t stream) {
  const float* hidden = (const float*)d_in[0];
  const float* amask = (const float*)d_in[1];
  const int* ind = (const int*)d_in[3];
  const int* outd = (const int*)d_in[4];
  const int* spe = (const int*)d_in[5];
  const float* Wq = (const float*)d_in[8];
  const float* bq = (const float*)d_in[9];
  const float* Wk = (const float*)d_in[10];
  const float* bk = (const float*)d_in[11];
  const float* Wv = (const float*)d_in[12];
  const float* bv = (const float*)d_in[13];
  const float* Win = (const float*)d_in[14];
  const float* Wout = (const float*)d_in[15];
  const float* Wspe = (const float*)d_in[16];

  char* ws = (char*)d_ws;
  const size_t BSD = (size_t)Bc * Sc * Dc;
  unsigned short* hbf = (unsigned short*)ws;                    // 16 MB
  unsigned short* Wtq = (unsigned short*)(ws + 16u * 1048576);  // 2 MB
  unsigned short* Wtk = (unsigned short*)(ws + 18u * 1048576);  // 2 MB
  unsigned short* Wtv = (unsigned short*)(ws + 20u * 1048576);  // 2 MB
  unsigned short* Qb = (unsigned short*)(ws + 24u * 1048576);   // 16 MB
  unsigned short* Kb = (unsigned short*)(ws + 40u * 1048576);   // 16 MB
  unsigned short* Vt = (unsigned short*)(ws + 56u * 1048576);   // 16 MB (transposed)
  float* ctx = (float*)d_out;
  float* probs = (float*)d_out + BSD;

  hipFuncSetAttribute((const void*)k_attn,
                      hipFuncAttributeMaxDynamicSharedMemorySize, 43648);

  k_pos_add<<<dim3(Bc * Sc), 256, 0, stream>>>(hidden, ind, outd, Win, Wout, hbf);
  k_wt<<<dim3(16, 16, 3), 256, 0, stream>>>(Wq, Wk, Wv, Wtq, Wtk, Wtv);
  k_gemm_mfma<<<dim3(8, 64, 3), 256, 0, stream>>>(hbf, Wtq, bq, Wtk, bk, Wtv, bv, Qb, Kb, Vt);
  k_attn<<<dim3(4096), 256, 43648, stream>>>(Qb, Kb, Vt, spe, Wspe, amask, probs, ctx);
}

// Round 6
// 302.568 us; speedup vs baseline: 1.3392x; 1.3392x over previous
//
#include <hip/hip_runtime.h>

#define Bc 16
#define Sc 512
#define Dc 1024
#define Hc 16
#define DHc 64

#define AS1 __attribute__((address_space(1)))
#define AS3 __attribute__((address_space(3)))

typedef __attribute__((ext_vector_type(8))) __bf16 bf16x8;
typedef __attribute__((ext_vector_type(4))) float f32x4;
typedef __attribute__((ext_vector_type(8))) unsigned short ushort8;

static __device__ __forceinline__ unsigned short f2bf(float f) {
  unsigned int u = __builtin_bit_cast(unsigned int, f);
  unsigned int r = (u + 0x7fffu + ((u >> 16) & 1u)) >> 16;  // RNE
  return (unsigned short)r;
}

// ---------------------------------------------------------------------------
// h_bf16 = bf16( hidden + (W_in*padmask)[in_degree] + (W_out*padmask)[out_degree] )
// ---------------------------------------------------------------------------
__global__ __launch_bounds__(256) void k_pos_add(
    const float* __restrict__ hidden, const int* __restrict__ ind,
    const int* __restrict__ outd, const float* __restrict__ Win,
    const float* __restrict__ Wout, unsigned short* __restrict__ hbf) {
  int row = blockIdx.x;
  int t = threadIdx.x;
  int id = ind[row], od = outd[row];
  float fi = (id != 0) ? 1.f : 0.f;
  float fo = (od != 0) ? 1.f : 0.f;
  float4 a = ((const float4*)(hidden + (size_t)row * Dc))[t];
  float4 x = ((const float4*)(Win + (size_t)id * Dc))[t];
  float4 y = ((const float4*)(Wout + (size_t)od * Dc))[t];
  ushort4 r;
  r.x = f2bf(a.x + fi * x.x + fo * y.x);
  r.y = f2bf(a.y + fi * x.y + fo * y.y);
  r.z = f2bf(a.z + fi * x.z + fo * y.z);
  r.w = f2bf(a.w + fi * x.w + fo * y.w);
  ((ushort4*)(hbf + (size_t)row * Dc))[t] = r;
}

// ---------------------------------------------------------------------------
// Wt[n][k] = bf16(W[k][n]) for q,k,v
// ---------------------------------------------------------------------------
__global__ __launch_bounds__(256) void k_wt(
    const float* __restrict__ Wq, const float* __restrict__ Wk,
    const float* __restrict__ Wv, unsigned short* __restrict__ Wtq,
    unsigned short* __restrict__ Wtk, unsigned short* __restrict__ Wtv) {
  const float* W = blockIdx.z == 0 ? Wq : blockIdx.z == 1 ? Wk : Wv;
  unsigned short* Wt = blockIdx.z == 0 ? Wtq : blockIdx.z == 1 ? Wtk : Wtv;
  __shared__ float tile[64][65];
  int k0 = blockIdx.y * 64, n0 = blockIdx.x * 64;
  int r = threadIdx.x >> 4, c4 = (threadIdx.x & 15) * 4;
  for (int rr = r; rr < 64; rr += 16) {
    float4 v = *(const float4*)(W + (size_t)(k0 + rr) * Dc + n0 + c4);
    tile[rr][c4 + 0] = v.x;
    tile[rr][c4 + 1] = v.y;
    tile[rr][c4 + 2] = v.z;
    tile[rr][c4 + 3] = v.w;
  }
  __syncthreads();
  for (int rr = r; rr < 64; rr += 16) {
    ushort4 o;
    o.x = f2bf(tile[c4 + 0][rr]);
    o.y = f2bf(tile[c4 + 1][rr]);
    o.z = f2bf(tile[c4 + 2][rr]);
    o.w = f2bf(tile[c4 + 3][rr]);
    *(ushort4*)(Wt + (size_t)(n0 + rr) * Dc + k0 + c4) = o;
  }
}

// ---------------------------------------------------------------------------
// QKV projections, bf16 MFMA. Q,K row-major [b,s,1024];
// V pre-transposed: Vt[(b*16+h), dh, s].
// ---------------------------------------------------------------------------
__global__ __launch_bounds__(256) void k_gemm_mfma(
    const unsigned short* __restrict__ hbf,
    const unsigned short* __restrict__ Wtq, const float* __restrict__ bq,
    const unsigned short* __restrict__ Wtk, const float* __restrict__ bk,
    const unsigned short* __restrict__ Wtv, const float* __restrict__ bv,
    unsigned short* __restrict__ Qo, unsigned short* __restrict__ Ko,
    unsigned short* __restrict__ Vt) {
  int zsel = blockIdx.z;
  const unsigned short* Wt;
  const float* bias;
  if (zsel == 0) { Wt = Wtq; bias = bq; }
  else if (zsel == 1) { Wt = Wtk; bias = bk; }
  else { Wt = Wtv; bias = bv; }

  __shared__ __align__(16) unsigned short As[128 * 32];
  __shared__ __align__(16) unsigned short Bs[128 * 32];

  int tid = threadIdx.x, lane = tid & 63, wave = tid >> 6;
  int m0 = blockIdx.y * 128, n0 = blockIdx.x * 128;
  int wr = wave >> 1, wc = wave & 1;

  f32x4 acc[4][4] = {};

  int srow = lane >> 2;
  int skb = (lane & 3) * 8;
  const unsigned short* gA = hbf + (size_t)(m0 + srow) * Dc + skb;
  const unsigned short* gB = Wt + (size_t)(n0 + srow) * Dc + skb;

  int fr = lane & 15, kg = (lane >> 4) * 8;

  for (int k0 = 0; k0 < Dc; k0 += 32) {
#pragma unroll
    for (int cc = 0; cc < 2; ++cc) {
      int c = wave + cc * 4;
      __builtin_amdgcn_global_load_lds(
          (const AS1 void*)(gA + (size_t)c * 16 * Dc + k0),
          (AS3 void*)(As + c * 16 * 32), 16, 0, 0);
      __builtin_amdgcn_global_load_lds(
          (const AS1 void*)(gB + (size_t)c * 16 * Dc + k0),
          (AS3 void*)(Bs + c * 16 * 32), 16, 0, 0);
    }
    __syncthreads();

    bf16x8 af[4], bfr[4];
#pragma unroll
    for (int m = 0; m < 4; ++m)
      af[m] = *(const bf16x8*)(As + (wr * 64 + m * 16 + fr) * 32 + kg);
#pragma unroll
    for (int n = 0; n < 4; ++n)
      bfr[n] = *(const bf16x8*)(Bs + (wc * 64 + n * 16 + fr) * 32 + kg);
#pragma unroll
    for (int m = 0; m < 4; ++m)
#pragma unroll
      for (int n = 0; n < 4; ++n)
        acc[m][n] = __builtin_amdgcn_mfma_f32_16x16x32_bf16(af[m], bfr[n], acc[m][n], 0, 0, 0);
    __syncthreads();
  }

  int fq = lane >> 4;
  if (zsel < 2) {
    unsigned short* C = (zsel == 0) ? Qo : Ko;
#pragma unroll
    for (int m = 0; m < 4; ++m) {
#pragma unroll
      for (int n = 0; n < 4; ++n) {
        int col = n0 + wc * 64 + n * 16 + fr;
        float bb = bias[col];
#pragma unroll
        for (int r = 0; r < 4; ++r) {
          int row = m0 + wr * 64 + m * 16 + fq * 4 + r;
          C[(size_t)row * Dc + col] = f2bf(acc[m][n][r] + bb);
        }
      }
    }
  } else {
#pragma unroll
    for (int m = 0; m < 4; ++m) {
#pragma unroll
      for (int n = 0; n < 4; ++n) {
        int col = n0 + wc * 64 + n * 16 + fr;
        int hh = col >> 6, dh = col & 63;
        float bb = bias[col];
        int row = m0 + wr * 64 + m * 16 + fq * 4;
        int bb_ = row >> 9, ss = row & 511;
        ushort4 pk;
        pk.x = f2bf(acc[m][n][0] + bb);
        pk.y = f2bf(acc[m][n][1] + bb);
        pk.z = f2bf(acc[m][n][2] + bb);
        pk.w = f2bf(acc[m][n][3] + bb);
        *(ushort4*)(Vt + ((size_t)(bb_ * Hc + hh) * DHc + dh) * Sc + ss) = pk;
      }
    }
  }
}

// ---------------------------------------------------------------------------
// Fused attention, barrier-minimal: block = (b, h, 32 q-rows); 4 waves.
// B-operands (K rows, V^T rows) loaded DIRECTLY from global as MFMA frags
// (L2-resident; no LDS staging, no staging barriers). 2 barriers total.
// S fp32 [32][516] in LDS. LDS = 68224 B -> 2 blocks/CU.
// ---------------------------------------------------------------------------
#define SW 516
__global__ __launch_bounds__(256) void k_attn(
    const unsigned short* __restrict__ Qb, const unsigned short* __restrict__ Kb,
    const unsigned short* __restrict__ Vt, const int* __restrict__ spe,
    const float* __restrict__ Wspe, const float* __restrict__ mask,
    float* __restrict__ probs, float* __restrict__ ctx) {
  extern __shared__ char smem[];
  float* S = (float*)smem;                       // 32*516*4 = 66048
  float* Wb = (float*)(smem + 66048);            // 2048
  float* Rinv = (float*)(smem + 66048 + 2048);   // 128

  int tid = threadIdx.x, lane = tid & 63, w = tid >> 6;
  int fr = lane & 15, fq = lane >> 4, kg8 = fq * 8;
  int qh = w & 1, wh = w >> 1;

  int flat = blockIdx.x;
  int swz = (flat & 7) * 512 + (flat >> 3);
  int qt = swz & 15, h = (swz >> 4) & 15, b = swz >> 8;
  int q0 = qt * 32;

  for (int i = tid; i < 512; i += 256) Wb[i] = Wspe[i * Hc + h];

  // Q fragments in registers for the whole QK^T phase
  const unsigned short* qbase = Qb + (size_t)(b * Sc + q0) * Dc + h * DHc;
  bf16x8 af[2];
#pragma unroll
  for (int kk = 0; kk < 2; ++kk)
    af[kk] = *(const bf16x8*)(qbase + (size_t)(qh * 16 + fr) * Dc + kk * 32 + kg8);

  // ---- QK^T: B-frags direct from global; no barriers in loop ----
  const unsigned short* kbase = Kb + (size_t)(b * Sc) * Dc + h * DHc;
  for (int it = 0; it < 8; ++it) {
    bf16x8 bf_[2][2];
#pragma unroll
    for (int nf = 0; nf < 2; ++nf)
#pragma unroll
      for (int kk = 0; kk < 2; ++kk) {
        int brow = it * 64 + wh * 32 + nf * 16 + fr;
        bf_[nf][kk] = *(const bf16x8*)(kbase + (size_t)brow * Dc + kk * 32 + kg8);
      }
#pragma unroll
    for (int nf = 0; nf < 2; ++nf) {
      f32x4 acc = {};
#pragma unroll
      for (int kk = 0; kk < 2; ++kk)
        acc = __builtin_amdgcn_mfma_f32_16x16x32_bf16(af[kk], bf_[nf][kk], acc, 0, 0, 0);
#pragma unroll
      for (int r = 0; r < 4; ++r)
        S[(qh * 16 + fq * 4 + r) * SW + it * 64 + wh * 32 + nf * 16 + fr] = acc[r] * 0.125f;
    }
  }
  __syncthreads();  // barrier 1: S complete, Wb ready

  // ---- softmax: wave handles rows w*8..w*8+7; lanes cover cols contiguous ----
  {
    float4 mk0 = *(const float4*)(mask + b * Sc + lane * 4);
    float4 mk1 = *(const float4*)(mask + b * Sc + 256 + lane * 4);
    for (int r8 = 0; r8 < 8; ++r8) {
      int row = w * 8 + r8;
      float* sp = S + row * SW;
      const int* spp = spe + (size_t)(b * Sc + q0 + row) * Sc;
      float4 s0 = *(float4*)(sp + lane * 4);
      float4 s1 = *(float4*)(sp + 256 + lane * 4);
      int4 i0 = *(const int4*)(spp + lane * 4);
      int4 i1 = *(const int4*)(spp + 256 + lane * 4);
      s0.x += Wb[i0.x] + mk0.x; s0.y += Wb[i0.y] + mk0.y;
      s0.z += Wb[i0.z] + mk0.z; s0.w += Wb[i0.w] + mk0.w;
      s1.x += Wb[i1.x] + mk1.x; s1.y += Wb[i1.y] + mk1.y;
      s1.z += Wb[i1.z] + mk1.z; s1.w += Wb[i1.w] + mk1.w;
      float mx = fmaxf(fmaxf(fmaxf(s0.x, s0.y), fmaxf(s0.z, s0.w)),
                       fmaxf(fmaxf(s1.x, s1.y), fmaxf(s1.z, s1.w)));
#pragma unroll
      for (int o = 32; o; o >>= 1) mx = fmaxf(mx, __shfl_xor(mx, o));
      s0.x = __expf(s0.x - mx); s0.y = __expf(s0.y - mx);
      s0.z = __expf(s0.z - mx); s0.w = __expf(s0.w - mx);
      s1.x = __expf(s1.x - mx); s1.y = __expf(s1.y - mx);
      s1.z = __expf(s1.z - mx); s1.w = __expf(s1.w - mx);
      float sum = s0.x + s0.y + s0.z + s0.w + s1.x + s1.y + s1.z + s1.w;
#pragma unroll
      for (int o = 32; o; o >>= 1) sum += __shfl_xor(sum, o);
      *(float4*)(sp + lane * 4) = s0;
      *(float4*)(sp + 256 + lane * 4) = s1;
      if (lane == 0) Rinv[row] = 1.f / sum;
    }
  }
  __syncthreads();  // barrier 2: exp(S), Rinv complete

  // ---- PV (B-frags direct from Vt) + overlapped probs write ----
  const unsigned short* vtbase = Vt + (size_t)(b * Hc + h) * DHc * Sc;
  float* pbase = probs + (size_t)((b * Hc + h) * Sc + q0) * Sc;
  int prow = tid >> 3, pc0 = (tid & 7) * 8;
  float prv = Rinv[prow];
  f32x4 pacc[2] = {};
  for (int it = 0; it < 8; ++it) {
    bf16x8 bf_[2][2];
#pragma unroll
    for (int nf = 0; nf < 2; ++nf)
#pragma unroll
      for (int kk = 0; kk < 2; ++kk) {
        int dhrow = wh * 32 + nf * 16 + fr;
        bf_[nf][kk] = *(const bf16x8*)(vtbase + (size_t)dhrow * Sc + it * 64 + kk * 32 + kg8);
      }
    {  // probs slab for this it (overlaps with MFMA below)
      float4 e0 = *(float4*)(S + prow * SW + it * 64 + pc0);
      float4 e1 = *(float4*)(S + prow * SW + it * 64 + pc0 + 4);
      e0.x *= prv; e0.y *= prv; e0.z *= prv; e0.w *= prv;
      e1.x *= prv; e1.y *= prv; e1.z *= prv; e1.w *= prv;
      *(float4*)(pbase + (size_t)prow * Sc + it * 64 + pc0) = e0;
      *(float4*)(pbase + (size_t)prow * Sc + it * 64 + pc0 + 4) = e1;
    }
#pragma unroll
    for (int kk = 0; kk < 2; ++kk) {
      const float* s2 = S + (qh * 16 + fr) * SW + it * 64 + kk * 32 + kg8;
      float4 a0 = *(const float4*)(s2);
      float4 a1 = *(const float4*)(s2 + 4);
      bf16x8 afr;
      afr[0] = (__bf16)a0.x; afr[1] = (__bf16)a0.y;
      afr[2] = (__bf16)a0.z; afr[3] = (__bf16)a0.w;
      afr[4] = (__bf16)a1.x; afr[5] = (__bf16)a1.y;
      afr[6] = (__bf16)a1.z; afr[7] = (__bf16)a1.w;
#pragma unroll
      for (int nf = 0; nf < 2; ++nf)
        pacc[nf] = __builtin_amdgcn_mfma_f32_16x16x32_bf16(afr, bf_[nf][kk], pacc[nf], 0, 0, 0);
    }
  }

  // ---- ctx epilogue ----
  float* cbase = ctx + (size_t)(b * Sc + q0 + qh * 16) * Dc + h * DHc + wh * 32;
#pragma unroll
  for (int nf = 0; nf < 2; ++nf)
#pragma unroll
    for (int r = 0; r < 4; ++r) {
      int row = fq * 4 + r;
      cbase[(size_t)row * Dc + nf * 16 + fr] = pacc[nf][r] * Rinv[qh * 16 + row];
    }
}

extern "C" void kernel_launch(void* const* d_in, const int* in_sizes, int n_in,
                              void* d_out, int out_size, void* d_ws, size_t ws_size,
                              hipStream_t stream) {
  const float* hidden = (const float*)d_in[0];
  const float* amask = (const float*)d_in[1];
  const int* ind = (const int*)d_in[3];
  const int* outd = (const int*)d_in[4];
  const int* spe = (const int*)d_in[5];
  const float* Wq = (const float*)d_in[8];
  const float* bq = (const float*)d_in[9];
  const float* Wk = (const float*)d_in[10];
  const float* bk = (const float*)d_in[11];
  const float* Wv = (const float*)d_in[12];
  const float* bv = (const float*)d_in[13];
  const float* Win = (const float*)d_in[14];
  const float* Wout = (const float*)d_in[15];
  const float* Wspe = (const float*)d_in[16];

  char* ws = (char*)d_ws;
  const size_t BSD = (size_t)Bc * Sc * Dc;
  unsigned short* hbf = (unsigned short*)ws;                    // 16 MB
  unsigned short* Wtq = (unsigned short*)(ws + 16u * 1048576);  // 2 MB
  unsigned short* Wtk = (unsigned short*)(ws + 18u * 1048576);  // 2 MB
  unsigned short* Wtv = (unsigned short*)(ws + 20u * 1048576);  // 2 MB
  unsigned short* Qb = (unsigned short*)(ws + 24u * 1048576);   // 16 MB
  unsigned short* Kb = (unsigned short*)(ws + 40u * 1048576);   // 16 MB
  unsigned short* Vt = (unsigned short*)(ws + 56u * 1048576);   // 16 MB (transposed)
  float* ctx = (float*)d_out;
  float* probs = (float*)d_out + BSD;

  hipFuncSetAttribute((const void*)k_attn,
                      hipFuncAttributeMaxDynamicSharedMemorySize, 68224);

  k_pos_add<<<dim3(Bc * Sc), 256, 0, stream>>>(hidden, ind, outd, Win, Wout, hbf);
  k_wt<<<dim3(16, 16, 3), 256, 0, stream>>>(Wq, Wk, Wv, Wtq, Wtk, Wtv);
  k_gemm_mfma<<<dim3(8, 64, 3), 256, 0, stream>>>(hbf, Wtq, bq, Wtk, bk, Wtv, bv, Qb, Kb, Vt);
  k_attn<<<dim3(4096), 256, 68224, stream>>>(Qb, Kb, Vt, spe, Wspe, amask, probs, ctx);
}

// Round 7
// 271.241 us; speedup vs baseline: 1.4939x; 1.1155x over previous
//
#include <hip/hip_runtime.h>

#define Bc 16
#define Sc 512
#define Dc 1024
#define Hc 16
#define DHc 64

#define AS1 __attribute__((address_space(1)))
#define AS3 __attribute__((address_space(3)))

typedef __attribute__((ext_vector_type(8))) __bf16 bf16x8;
typedef __attribute__((ext_vector_type(4))) float f32x4;
typedef __attribute__((ext_vector_type(8))) unsigned short ushort8;

static __device__ __forceinline__ unsigned short f2bf(float f) {
  unsigned int u = __builtin_bit_cast(unsigned int, f);
  unsigned int r = (u + 0x7fffu + ((u >> 16) & 1u)) >> 16;  // RNE
  return (unsigned short)r;
}
static __device__ __forceinline__ float bf2f(unsigned short u) {
  unsigned int x = ((unsigned int)u) << 16;
  return __builtin_bit_cast(float, x);
}

// ---------------------------------------------------------------------------
// h_bf16 = bf16( hidden + (W_in*padmask)[in_degree] + (W_out*padmask)[out_degree] )
// ---------------------------------------------------------------------------
__global__ __launch_bounds__(256) void k_pos_add(
    const float* __restrict__ hidden, const int* __restrict__ ind,
    const int* __restrict__ outd, const float* __restrict__ Win,
    const float* __restrict__ Wout, unsigned short* __restrict__ hbf) {
  int row = blockIdx.x;
  int t = threadIdx.x;
  int id = ind[row], od = outd[row];
  float fi = (id != 0) ? 1.f : 0.f;
  float fo = (od != 0) ? 1.f : 0.f;
  float4 a = ((const float4*)(hidden + (size_t)row * Dc))[t];
  float4 x = ((const float4*)(Win + (size_t)id * Dc))[t];
  float4 y = ((const float4*)(Wout + (size_t)od * Dc))[t];
  ushort4 r;
  r.x = f2bf(a.x + fi * x.x + fo * y.x);
  r.y = f2bf(a.y + fi * x.y + fo * y.y);
  r.z = f2bf(a.z + fi * x.z + fo * y.z);
  r.w = f2bf(a.w + fi * x.w + fo * y.w);
  ((ushort4*)(hbf + (size_t)row * Dc))[t] = r;
}

// ---------------------------------------------------------------------------
// Wt[n][k] = bf16(W[k][n]) for q,k,v
// ---------------------------------------------------------------------------
__global__ __launch_bounds__(256) void k_wt(
    const float* __restrict__ Wq, const float* __restrict__ Wk,
    const float* __restrict__ Wv, unsigned short* __restrict__ Wtq,
    unsigned short* __restrict__ Wtk, unsigned short* __restrict__ Wtv) {
  const float* W = blockIdx.z == 0 ? Wq : blockIdx.z == 1 ? Wk : Wv;
  unsigned short* Wt = blockIdx.z == 0 ? Wtq : blockIdx.z == 1 ? Wtk : Wtv;
  __shared__ float tile[64][65];
  int k0 = blockIdx.y * 64, n0 = blockIdx.x * 64;
  int r = threadIdx.x >> 4, c4 = (threadIdx.x & 15) * 4;
  for (int rr = r; rr < 64; rr += 16) {
    float4 v = *(const float4*)(W + (size_t)(k0 + rr) * Dc + n0 + c4);
    tile[rr][c4 + 0] = v.x;
    tile[rr][c4 + 1] = v.y;
    tile[rr][c4 + 2] = v.z;
    tile[rr][c4 + 3] = v.w;
  }
  __syncthreads();
  for (int rr = r; rr < 64; rr += 16) {
    ushort4 o;
    o.x = f2bf(tile[c4 + 0][rr]);
    o.y = f2bf(tile[c4 + 1][rr]);
    o.z = f2bf(tile[c4 + 2][rr]);
    o.w = f2bf(tile[c4 + 3][rr]);
    *(ushort4*)(Wt + (size_t)(n0 + rr) * Dc + k0 + c4) = o;
  }
}

// ---------------------------------------------------------------------------
// QKV projections, bf16 MFMA. Q pre-scaled by 1/8 (exact in bf16).
// Q,K row-major [b,s,1024]; V pre-transposed: Vt[(b*16+h), dh, s].
// ---------------------------------------------------------------------------
__global__ __launch_bounds__(256) void k_gemm_mfma(
    const unsigned short* __restrict__ hbf,
    const unsigned short* __restrict__ Wtq, const float* __restrict__ bq,
    const unsigned short* __restrict__ Wtk, const float* __restrict__ bk,
    const unsigned short* __restrict__ Wtv, const float* __restrict__ bv,
    unsigned short* __restrict__ Qo, unsigned short* __restrict__ Ko,
    unsigned short* __restrict__ Vt) {
  int zsel = blockIdx.z;
  const unsigned short* Wt;
  const float* bias;
  if (zsel == 0) { Wt = Wtq; bias = bq; }
  else if (zsel == 1) { Wt = Wtk; bias = bk; }
  else { Wt = Wtv; bias = bv; }

  __shared__ __align__(16) unsigned short As[128 * 32];
  __shared__ __align__(16) unsigned short Bs[128 * 32];

  int tid = threadIdx.x, lane = tid & 63, wave = tid >> 6;
  int m0 = blockIdx.y * 128, n0 = blockIdx.x * 128;
  int wr = wave >> 1, wc = wave & 1;

  f32x4 acc[4][4] = {};

  int srow = lane >> 2;
  int skb = (lane & 3) * 8;
  const unsigned short* gA = hbf + (size_t)(m0 + srow) * Dc + skb;
  const unsigned short* gB = Wt + (size_t)(n0 + srow) * Dc + skb;

  int fr = lane & 15, kg = (lane >> 4) * 8;

  for (int k0 = 0; k0 < Dc; k0 += 32) {
#pragma unroll
    for (int cc = 0; cc < 2; ++cc) {
      int c = wave + cc * 4;
      __builtin_amdgcn_global_load_lds(
          (const AS1 void*)(gA + (size_t)c * 16 * Dc + k0),
          (AS3 void*)(As + c * 16 * 32), 16, 0, 0);
      __builtin_amdgcn_global_load_lds(
          (const AS1 void*)(gB + (size_t)c * 16 * Dc + k0),
          (AS3 void*)(Bs + c * 16 * 32), 16, 0, 0);
    }
    __syncthreads();

    bf16x8 af[4], bfr[4];
#pragma unroll
    for (int m = 0; m < 4; ++m)
      af[m] = *(const bf16x8*)(As + (wr * 64 + m * 16 + fr) * 32 + kg);
#pragma unroll
    for (int n = 0; n < 4; ++n)
      bfr[n] = *(const bf16x8*)(Bs + (wc * 64 + n * 16 + fr) * 32 + kg);
#pragma unroll
    for (int m = 0; m < 4; ++m)
#pragma unroll
      for (int n = 0; n < 4; ++n)
        acc[m][n] = __builtin_amdgcn_mfma_f32_16x16x32_bf16(af[m], bfr[n], acc[m][n], 0, 0, 0);
    __syncthreads();
  }

  int fq = lane >> 4;
  if (zsel < 2) {
    unsigned short* C = (zsel == 0) ? Qo : Ko;
    float scale = (zsel == 0) ? 0.125f : 1.f;  // fold 1/sqrt(64) into Q (exact)
#pragma unroll
    for (int m = 0; m < 4; ++m) {
#pragma unroll
      for (int n = 0; n < 4; ++n) {
        int col = n0 + wc * 64 + n * 16 + fr;
        float bb = bias[col];
#pragma unroll
        for (int r = 0; r < 4; ++r) {
          int row = m0 + wr * 64 + m * 16 + fq * 4 + r;
          C[(size_t)row * Dc + col] = f2bf((acc[m][n][r] + bb) * scale);
        }
      }
    }
  } else {
#pragma unroll
    for (int m = 0; m < 4; ++m) {
#pragma unroll
      for (int n = 0; n < 4; ++n) {
        int col = n0 + wc * 64 + n * 16 + fr;
        int hh = col >> 6, dh = col & 63;
        float bb = bias[col];
        int row = m0 + wr * 64 + m * 16 + fq * 4;
        int bb_ = row >> 9, ss = row & 511;
        ushort4 pk;
        pk.x = f2bf(acc[m][n][0] + bb);
        pk.y = f2bf(acc[m][n][1] + bb);
        pk.z = f2bf(acc[m][n][2] + bb);
        pk.w = f2bf(acc[m][n][3] + bb);
        *(ushort4*)(Vt + ((size_t)(bb_ * Hc + hh) * DHc + dh) * Sc + ss) = pk;
      }
    }
  }
}

// ---------------------------------------------------------------------------
// Fused attention, barrier-minimal: block = (b, h, 32 q-rows); 4 waves.
// B-operands direct from global (L2-resident). S stored bf16 [32][520]
// -> LDS 35456 B -> 4 blocks/CU. 2 barriers total.
// ---------------------------------------------------------------------------
#define SWB 520
__global__ __launch_bounds__(256) void k_attn(
    const unsigned short* __restrict__ Qb, const unsigned short* __restrict__ Kb,
    const unsigned short* __restrict__ Vt, const int* __restrict__ spe,
    const float* __restrict__ Wspe, const float* __restrict__ mask,
    float* __restrict__ probs, float* __restrict__ ctx) {
  extern __shared__ char smem[];
  unsigned short* S = (unsigned short*)smem;     // 32*520*2 = 33280
  float* Wb = (float*)(smem + 33280);            // 2048
  float* Rinv = (float*)(smem + 33280 + 2048);   // 128

  int tid = threadIdx.x, lane = tid & 63, w = tid >> 6;
  int fr = lane & 15, fq = lane >> 4, kg8 = fq * 8;
  int qh = w & 1, wh = w >> 1;

  int flat = blockIdx.x;
  int swz = (flat & 7) * 512 + (flat >> 3);
  int qt = swz & 15, h = (swz >> 4) & 15, b = swz >> 8;
  int q0 = qt * 32;

  for (int i = tid; i < 512; i += 256) Wb[i] = Wspe[i * Hc + h];

  // Q fragments (pre-scaled by 1/8) in registers for the whole QK^T phase
  const unsigned short* qbase = Qb + (size_t)(b * Sc + q0) * Dc + h * DHc;
  bf16x8 af[2];
#pragma unroll
  for (int kk = 0; kk < 2; ++kk)
    af[kk] = *(const bf16x8*)(qbase + (size_t)(qh * 16 + fr) * Dc + kk * 32 + kg8);

  // ---- QK^T: B-frags direct from global; no barriers in loop ----
  const unsigned short* kbase = Kb + (size_t)(b * Sc) * Dc + h * DHc;
  for (int it = 0; it < 8; ++it) {
    bf16x8 bf_[2][2];
#pragma unroll
    for (int nf = 0; nf < 2; ++nf)
#pragma unroll
      for (int kk = 0; kk < 2; ++kk) {
        int brow = it * 64 + wh * 32 + nf * 16 + fr;
        bf_[nf][kk] = *(const bf16x8*)(kbase + (size_t)brow * Dc + kk * 32 + kg8);
      }
#pragma unroll
    for (int nf = 0; nf < 2; ++nf) {
      f32x4 acc = {};
#pragma unroll
      for (int kk = 0; kk < 2; ++kk)
        acc = __builtin_amdgcn_mfma_f32_16x16x32_bf16(af[kk], bf_[nf][kk], acc, 0, 0, 0);
#pragma unroll
      for (int r = 0; r < 4; ++r)
        S[(qh * 16 + fq * 4 + r) * SWB + it * 64 + wh * 32 + nf * 16 + fr] = f2bf(acc[r]);
    }
  }
  __syncthreads();  // barrier 1: S complete, Wb ready

  // ---- softmax: wave handles rows w*8..w*8+7; lane covers 8 contiguous cols ----
  {
    float4 mk0 = *(const float4*)(mask + b * Sc + lane * 8);
    float4 mk1 = *(const float4*)(mask + b * Sc + lane * 8 + 4);
    for (int r8 = 0; r8 < 8; ++r8) {
      int row = w * 8 + r8;
      unsigned short* sp = S + row * SWB + lane * 8;
      const int* spp = spe + (size_t)(b * Sc + q0 + row) * Sc + lane * 8;
      ushort8 sv = *(const ushort8*)sp;
      int4 i0 = *(const int4*)(spp);
      int4 i1 = *(const int4*)(spp + 4);
      float v0 = bf2f(sv[0]) + Wb[i0.x] + mk0.x;
      float v1 = bf2f(sv[1]) + Wb[i0.y] + mk0.y;
      float v2 = bf2f(sv[2]) + Wb[i0.z] + mk0.z;
      float v3 = bf2f(sv[3]) + Wb[i0.w] + mk0.w;
      float v4 = bf2f(sv[4]) + Wb[i1.x] + mk1.x;
      float v5 = bf2f(sv[5]) + Wb[i1.y] + mk1.y;
      float v6 = bf2f(sv[6]) + Wb[i1.z] + mk1.z;
      float v7 = bf2f(sv[7]) + Wb[i1.w] + mk1.w;
      float mx = fmaxf(fmaxf(fmaxf(v0, v1), fmaxf(v2, v3)),
                       fmaxf(fmaxf(v4, v5), fmaxf(v6, v7)));
#pragma unroll
      for (int o = 32; o; o >>= 1) mx = fmaxf(mx, __shfl_xor(mx, o));
      float e0 = __expf(v0 - mx), e1 = __expf(v1 - mx);
      float e2 = __expf(v2 - mx), e3 = __expf(v3 - mx);
      float e4 = __expf(v4 - mx), e5 = __expf(v5 - mx);
      float e6 = __expf(v6 - mx), e7 = __expf(v7 - mx);
      float sum = e0 + e1 + e2 + e3 + e4 + e5 + e6 + e7;
#pragma unroll
      for (int o = 32; o; o >>= 1) sum += __shfl_xor(sum, o);
      ushort8 ev;
      ev[0] = f2bf(e0); ev[1] = f2bf(e1); ev[2] = f2bf(e2); ev[3] = f2bf(e3);
      ev[4] = f2bf(e4); ev[5] = f2bf(e5); ev[6] = f2bf(e6); ev[7] = f2bf(e7);
      *(ushort8*)sp = ev;
      if (lane == 0) Rinv[row] = 1.f / sum;
    }
  }
  __syncthreads();  // barrier 2: exp(S) bf16, Rinv complete

  // ---- PV (B-frags direct from Vt, A-frags direct ds_read) + probs write ----
  const unsigned short* vtbase = Vt + (size_t)(b * Hc + h) * DHc * Sc;
  float* pbase = probs + (size_t)((b * Hc + h) * Sc + q0) * Sc;
  int prow = tid >> 3, pc0 = (tid & 7) * 8;
  float prv = Rinv[prow];
  f32x4 pacc[2] = {};
  for (int it = 0; it < 8; ++it) {
    bf16x8 bf_[2][2];
#pragma unroll
    for (int nf = 0; nf < 2; ++nf)
#pragma unroll
      for (int kk = 0; kk < 2; ++kk) {
        int dhrow = wh * 32 + nf * 16 + fr;
        bf_[nf][kk] = *(const bf16x8*)(vtbase + (size_t)dhrow * Sc + it * 64 + kk * 32 + kg8);
      }
    {  // probs slab for this it (overlaps with MFMA below)
      ushort8 sv = *(const ushort8*)(S + prow * SWB + it * 64 + pc0);
      float4 e0, e1;
      e0.x = bf2f(sv[0]) * prv; e0.y = bf2f(sv[1]) * prv;
      e0.z = bf2f(sv[2]) * prv; e0.w = bf2f(sv[3]) * prv;
      e1.x = bf2f(sv[4]) * prv; e1.y = bf2f(sv[5]) * prv;
      e1.z = bf2f(sv[6]) * prv; e1.w = bf2f(sv[7]) * prv;
      *(float4*)(pbase + (size_t)prow * Sc + it * 64 + pc0) = e0;
      *(float4*)(pbase + (size_t)prow * Sc + it * 64 + pc0 + 4) = e1;
    }
#pragma unroll
    for (int kk = 0; kk < 2; ++kk) {
      bf16x8 afr = *(const bf16x8*)(S + (qh * 16 + fr) * SWB + it * 64 + kk * 32 + kg8);
#pragma unroll
      for (int nf = 0; nf < 2; ++nf)
        pacc[nf] = __builtin_amdgcn_mfma_f32_16x16x32_bf16(afr, bf_[nf][kk], pacc[nf], 0, 0, 0);
    }
  }

  // ---- ctx epilogue ----
  float* cbase = ctx + (size_t)(b * Sc + q0 + qh * 16) * Dc + h * DHc + wh * 32;
#pragma unroll
  for (int nf = 0; nf < 2; ++nf)
#pragma unroll
    for (int r = 0; r < 4; ++r) {
      int row = fq * 4 + r;
      cbase[(size_t)row * Dc + nf * 16 + fr] = pacc[nf][r] * Rinv[qh * 16 + row];
    }
}

extern "C" void kernel_launch(void* const* d_in, const int* in_sizes, int n_in,
                              void* d_out, int out_size, void* d_ws, size_t ws_size,
                              hipStream_t stream) {
  const float* hidden = (const float*)d_in[0];
  const float* amask = (const float*)d_in[1];
  const int* ind = (const int*)d_in[3];
  const int* outd = (const int*)d_in[4];
  const int* spe = (const int*)d_in[5];
  const float* Wq = (const float*)d_in[8];
  const float* bq = (const float*)d_in[9];
  const float* Wk = (const float*)d_in[10];
  const float* bk = (const float*)d_in[11];
  const float* Wv = (const float*)d_in[12];
  const float* bv = (const float*)d_in[13];
  const float* Win = (const float*)d_in[14];
  const float* Wout = (const float*)d_in[15];
  const float* Wspe = (const float*)d_in[16];

  char* ws = (char*)d_ws;
  const size_t BSD = (size_t)Bc * Sc * Dc;
  unsigned short* hbf = (unsigned short*)ws;                    // 16 MB
  unsigned short* Wtq = (unsigned short*)(ws + 16u * 1048576);  // 2 MB
  unsigned short* Wtk = (unsigned short*)(ws + 18u * 1048576);  // 2 MB
  unsigned short* Wtv = (unsigned short*)(ws + 20u * 1048576);  // 2 MB
  unsigned short* Qb = (unsigned short*)(ws + 24u * 1048576);   // 16 MB
  unsigned short* Kb = (unsigned short*)(ws + 40u * 1048576);   // 16 MB
  unsigned short* Vt = (unsigned short*)(ws + 56u * 1048576);   // 16 MB (transposed)
  float* ctx = (float*)d_out;
  float* probs = (float*)d_out + BSD;

  hipFuncSetAttribute((const void*)k_attn,
                      hipFuncAttributeMaxDynamicSharedMemorySize, 35456);

  k_pos_add<<<dim3(Bc * Sc), 256, 0, stream>>>(hidden, ind, outd, Win, Wout, hbf);
  k_wt<<<dim3(16, 16, 3), 256, 0, stream>>>(Wq, Wk, Wv, Wtq, Wtk, Wtv);
  k_gemm_mfma<<<dim3(8, 64, 3), 256, 0, stream>>>(hbf, Wtq, bq, Wtk, bk, Wtv, bv, Qb, Kb, Vt);
  k_attn<<<dim3(4096), 256, 35456, stream>>>(Qb, Kb, Vt, spe, Wspe, amask, probs, ctx);
}

// Round 8
// 262.446 us; speedup vs baseline: 1.5439x; 1.0335x over previous
//
#include <hip/hip_runtime.h>

#define Bc 16
#define Sc 512
#define Dc 1024
#define Hc 16
#define DHc 64

#define AS1 __attribute__((address_space(1)))
#define AS3 __attribute__((address_space(3)))

typedef __attribute__((ext_vector_type(8))) __bf16 bf16x8;
typedef __attribute__((ext_vector_type(4))) float f32x4;
typedef __attribute__((ext_vector_type(8))) unsigned short ushort8;

static __device__ __forceinline__ unsigned short f2bf(float f) {
  unsigned int u = __builtin_bit_cast(unsigned int, f);
  unsigned int r = (u + 0x7fffu + ((u >> 16) & 1u)) >> 16;  // RNE
  return (unsigned short)r;
}
static __device__ __forceinline__ float bf2f(unsigned short u) {
  unsigned int x = ((unsigned int)u) << 16;
  return __builtin_bit_cast(float, x);
}

// ---------------------------------------------------------------------------
// h_bf16 = bf16( hidden + (W_in*padmask)[in_degree] + (W_out*padmask)[out_degree] )
// ---------------------------------------------------------------------------
__global__ __launch_bounds__(256) void k_pos_add(
    const float* __restrict__ hidden, const int* __restrict__ ind,
    const int* __restrict__ outd, const float* __restrict__ Win,
    const float* __restrict__ Wout, unsigned short* __restrict__ hbf) {
  int row = blockIdx.x;
  int t = threadIdx.x;
  int id = ind[row], od = outd[row];
  float fi = (id != 0) ? 1.f : 0.f;
  float fo = (od != 0) ? 1.f : 0.f;
  float4 a = ((const float4*)(hidden + (size_t)row * Dc))[t];
  float4 x = ((const float4*)(Win + (size_t)id * Dc))[t];
  float4 y = ((const float4*)(Wout + (size_t)od * Dc))[t];
  ushort4 r;
  r.x = f2bf(a.x + fi * x.x + fo * y.x);
  r.y = f2bf(a.y + fi * x.y + fo * y.y);
  r.z = f2bf(a.z + fi * x.z + fo * y.z);
  r.w = f2bf(a.w + fi * x.w + fo * y.w);
  ((ushort4*)(hbf + (size_t)row * Dc))[t] = r;
}

// ---------------------------------------------------------------------------
// Wt[n][k] = bf16(W[k][n]) for q,k,v
// ---------------------------------------------------------------------------
__global__ __launch_bounds__(256) void k_wt(
    const float* __restrict__ Wq, const float* __restrict__ Wk,
    const float* __restrict__ Wv, unsigned short* __restrict__ Wtq,
    unsigned short* __restrict__ Wtk, unsigned short* __restrict__ Wtv) {
  const float* W = blockIdx.z == 0 ? Wq : blockIdx.z == 1 ? Wk : Wv;
  unsigned short* Wt = blockIdx.z == 0 ? Wtq : blockIdx.z == 1 ? Wtk : Wtv;
  __shared__ float tile[64][65];
  int k0 = blockIdx.y * 64, n0 = blockIdx.x * 64;
  int r = threadIdx.x >> 4, c4 = (threadIdx.x & 15) * 4;
  for (int rr = r; rr < 64; rr += 16) {
    float4 v = *(const float4*)(W + (size_t)(k0 + rr) * Dc + n0 + c4);
    tile[rr][c4 + 0] = v.x;
    tile[rr][c4 + 1] = v.y;
    tile[rr][c4 + 2] = v.z;
    tile[rr][c4 + 3] = v.w;
  }
  __syncthreads();
  for (int rr = r; rr < 64; rr += 16) {
    ushort4 o;
    o.x = f2bf(tile[c4 + 0][rr]);
    o.y = f2bf(tile[c4 + 1][rr]);
    o.z = f2bf(tile[c4 + 2][rr]);
    o.w = f2bf(tile[c4 + 3][rr]);
    *(ushort4*)(Wt + (size_t)(n0 + rr) * Dc + k0 + c4) = o;
  }
}

// ---------------------------------------------------------------------------
// WspeT[h][i] = Wspe[i][h]  (coalesced per-head bias rows for k_attn)
// ---------------------------------------------------------------------------
__global__ __launch_bounds__(256) void k_wspet(
    const float* __restrict__ Wspe, float* __restrict__ WspeT) {
  int idx = blockIdx.x * 256 + threadIdx.x;  // 8192 total
  int h = idx >> 9, i = idx & 511;
  WspeT[idx] = Wspe[i * Hc + h];
}

// ---------------------------------------------------------------------------
// QKV projections, bf16 MFMA. Q pre-scaled by 1/8 (exact in bf16).
// Q,K row-major [b,s,1024]; V pre-transposed: Vt[(b*16+h), dh, s].
// ---------------------------------------------------------------------------
__global__ __launch_bounds__(256) void k_gemm_mfma(
    const unsigned short* __restrict__ hbf,
    const unsigned short* __restrict__ Wtq, const float* __restrict__ bq,
    const unsigned short* __restrict__ Wtk, const float* __restrict__ bk,
    const unsigned short* __restrict__ Wtv, const float* __restrict__ bv,
    unsigned short* __restrict__ Qo, unsigned short* __restrict__ Ko,
    unsigned short* __restrict__ Vt) {
  int zsel = blockIdx.z;
  const unsigned short* Wt;
  const float* bias;
  if (zsel == 0) { Wt = Wtq; bias = bq; }
  else if (zsel == 1) { Wt = Wtk; bias = bk; }
  else { Wt = Wtv; bias = bv; }

  __shared__ __align__(16) unsigned short As[128 * 32];
  __shared__ __align__(16) unsigned short Bs[128 * 32];

  int tid = threadIdx.x, lane = tid & 63, wave = tid >> 6;
  int m0 = blockIdx.y * 128, n0 = blockIdx.x * 128;
  int wr = wave >> 1, wc = wave & 1;

  f32x4 acc[4][4] = {};

  int srow = lane >> 2;
  int skb = (lane & 3) * 8;
  const unsigned short* gA = hbf + (size_t)(m0 + srow) * Dc + skb;
  const unsigned short* gB = Wt + (size_t)(n0 + srow) * Dc + skb;

  int fr = lane & 15, kg = (lane >> 4) * 8;

  for (int k0 = 0; k0 < Dc; k0 += 32) {
#pragma unroll
    for (int cc = 0; cc < 2; ++cc) {
      int c = wave + cc * 4;
      __builtin_amdgcn_global_load_lds(
          (const AS1 void*)(gA + (size_t)c * 16 * Dc + k0),
          (AS3 void*)(As + c * 16 * 32), 16, 0, 0);
      __builtin_amdgcn_global_load_lds(
          (const AS1 void*)(gB + (size_t)c * 16 * Dc + k0),
          (AS3 void*)(Bs + c * 16 * 32), 16, 0, 0);
    }
    __syncthreads();

    bf16x8 af[4], bfr[4];
#pragma unroll
    for (int m = 0; m < 4; ++m)
      af[m] = *(const bf16x8*)(As + (wr * 64 + m * 16 + fr) * 32 + kg);
#pragma unroll
    for (int n = 0; n < 4; ++n)
      bfr[n] = *(const bf16x8*)(Bs + (wc * 64 + n * 16 + fr) * 32 + kg);
#pragma unroll
    for (int m = 0; m < 4; ++m)
#pragma unroll
      for (int n = 0; n < 4; ++n)
        acc[m][n] = __builtin_amdgcn_mfma_f32_16x16x32_bf16(af[m], bfr[n], acc[m][n], 0, 0, 0);
    __syncthreads();
  }

  int fq = lane >> 4;
  if (zsel < 2) {
    unsigned short* C = (zsel == 0) ? Qo : Ko;
    float scale = (zsel == 0) ? 0.125f : 1.f;  // fold 1/sqrt(64) into Q (exact)
#pragma unroll
    for (int m = 0; m < 4; ++m) {
#pragma unroll
      for (int n = 0; n < 4; ++n) {
        int col = n0 + wc * 64 + n * 16 + fr;
        float bb = bias[col];
#pragma unroll
        for (int r = 0; r < 4; ++r) {
          int row = m0 + wr * 64 + m * 16 + fq * 4 + r;
          C[(size_t)row * Dc + col] = f2bf((acc[m][n][r] + bb) * scale);
        }
      }
    }
  } else {
#pragma unroll
    for (int m = 0; m < 4; ++m) {
#pragma unroll
      for (int n = 0; n < 4; ++n) {
        int col = n0 + wc * 64 + n * 16 + fr;
        int hh = col >> 6, dh = col & 63;
        float bb = bias[col];
        int row = m0 + wr * 64 + m * 16 + fq * 4;
        int bb_ = row >> 9, ss = row & 511;
        ushort4 pk;
        pk.x = f2bf(acc[m][n][0] + bb);
        pk.y = f2bf(acc[m][n][1] + bb);
        pk.z = f2bf(acc[m][n][2] + bb);
        pk.w = f2bf(acc[m][n][3] + bb);
        *(ushort4*)(Vt + ((size_t)(bb_ * Hc + hh) * DHc + dh) * Sc + ss) = pk;
      }
    }
  }
}

// ---------------------------------------------------------------------------
// Fused attention: block = (b, h, 16 q-rows); 4 waves; LDS 18752 B
// -> 8 blocks/CU (32 waves/CU, full cap). B-operands direct from global.
// QK^T: wave w owns k-cols it*64+w*16. PV: wave w owns dh w*16.
// ---------------------------------------------------------------------------
#define SWB 520
__global__ __launch_bounds__(256) void k_attn(
    const unsigned short* __restrict__ Qb, const unsigned short* __restrict__ Kb,
    const unsigned short* __restrict__ Vt, const int* __restrict__ spe,
    const float* __restrict__ WspeT, const float* __restrict__ mask,
    float* __restrict__ probs, float* __restrict__ ctx) {
  extern __shared__ char smem[];
  unsigned short* S = (unsigned short*)smem;     // 16*520*2 = 16640
  float* Wb = (float*)(smem + 16640);            // 2048
  float* Rinv = (float*)(smem + 16640 + 2048);   // 64

  int tid = threadIdx.x, lane = tid & 63, w = tid >> 6;
  int fr = lane & 15, fq = lane >> 4, kg8 = fq * 8;

  int flat = blockIdx.x;
  int swz = (flat & 7) * 1024 + (flat >> 3);
  int qt = swz & 31, h = (swz >> 5) & 15, b = swz >> 9;
  int q0 = qt * 16;

  // coalesced per-head bias row
  for (int i = tid; i < 512; i += 256) Wb[i] = WspeT[h * 512 + i];

  // Q fragments (pre-scaled by 1/8) in registers
  const unsigned short* qbase = Qb + (size_t)(b * Sc + q0) * Dc + h * DHc;
  bf16x8 af[2];
#pragma unroll
  for (int kk = 0; kk < 2; ++kk)
    af[kk] = *(const bf16x8*)(qbase + (size_t)fr * Dc + kk * 32 + kg8);

  // ---- QK^T: B-frags direct from global; no barriers in loop ----
  const unsigned short* kbase = Kb + (size_t)(b * Sc) * Dc + h * DHc;
  for (int it = 0; it < 8; ++it) {
    bf16x8 bf_[2];
#pragma unroll
    for (int kk = 0; kk < 2; ++kk) {
      int brow = it * 64 + w * 16 + fr;
      bf_[kk] = *(const bf16x8*)(kbase + (size_t)brow * Dc + kk * 32 + kg8);
    }
    f32x4 acc = {};
#pragma unroll
    for (int kk = 0; kk < 2; ++kk)
      acc = __builtin_amdgcn_mfma_f32_16x16x32_bf16(af[kk], bf_[kk], acc, 0, 0, 0);
#pragma unroll
    for (int r = 0; r < 4; ++r)
      S[(fq * 4 + r) * SWB + it * 64 + w * 16 + fr] = f2bf(acc[r]);
  }
  __syncthreads();  // barrier 1: S complete, Wb ready

  // ---- softmax: wave handles rows w*4..w*4+3; lane covers 8 contiguous cols ----
  {
    float4 mk0 = *(const float4*)(mask + b * Sc + lane * 8);
    float4 mk1 = *(const float4*)(mask + b * Sc + lane * 8 + 4);
    for (int r4 = 0; r4 < 4; ++r4) {
      int row = w * 4 + r4;
      unsigned short* sp = S + row * SWB + lane * 8;
      const int* spp = spe + (size_t)(b * Sc + q0 + row) * Sc + lane * 8;
      ushort8 sv = *(const ushort8*)sp;
      int4 i0 = *(const int4*)(spp);
      int4 i1 = *(const int4*)(spp + 4);
      float v0 = bf2f(sv[0]) + Wb[i0.x] + mk0.x;
      float v1 = bf2f(sv[1]) + Wb[i0.y] + mk0.y;
      float v2 = bf2f(sv[2]) + Wb[i0.z] + mk0.z;
      float v3 = bf2f(sv[3]) + Wb[i0.w] + mk0.w;
      float v4 = bf2f(sv[4]) + Wb[i1.x] + mk1.x;
      float v5 = bf2f(sv[5]) + Wb[i1.y] + mk1.y;
      float v6 = bf2f(sv[6]) + Wb[i1.z] + mk1.z;
      float v7 = bf2f(sv[7]) + Wb[i1.w] + mk1.w;
      float mx = fmaxf(fmaxf(fmaxf(v0, v1), fmaxf(v2, v3)),
                       fmaxf(fmaxf(v4, v5), fmaxf(v6, v7)));
#pragma unroll
      for (int o = 32; o; o >>= 1) mx = fmaxf(mx, __shfl_xor(mx, o));
      float e0 = __expf(v0 - mx), e1 = __expf(v1 - mx);
      float e2 = __expf(v2 - mx), e3 = __expf(v3 - mx);
      float e4 = __expf(v4 - mx), e5 = __expf(v5 - mx);
      float e6 = __expf(v6 - mx), e7 = __expf(v7 - mx);
      float sum = e0 + e1 + e2 + e3 + e4 + e5 + e6 + e7;
#pragma unroll
      for (int o = 32; o; o >>= 1) sum += __shfl_xor(sum, o);
      ushort8 ev;
      ev[0] = f2bf(e0); ev[1] = f2bf(e1); ev[2] = f2bf(e2); ev[3] = f2bf(e3);
      ev[4] = f2bf(e4); ev[5] = f2bf(e5); ev[6] = f2bf(e6); ev[7] = f2bf(e7);
      *(ushort8*)sp = ev;
      if (lane == 0) Rinv[row] = 1.f / sum;
    }
  }
  __syncthreads();  // barrier 2: exp(S) bf16, Rinv complete

  // ---- PV (B-frags direct from Vt, A-frags ds_read) + overlapped probs ----
  const unsigned short* vtbase = Vt + (size_t)(b * Hc + h) * DHc * Sc;
  float* pbase = probs + (size_t)((b * Hc + h) * Sc + q0) * Sc;
  int prow = tid >> 4, pc0 = (tid & 15) * 4;
  float prv = Rinv[prow];
  f32x4 pacc = {};
  for (int it = 0; it < 8; ++it) {
    bf16x8 bf_[2];
#pragma unroll
    for (int kk = 0; kk < 2; ++kk) {
      int dhrow = w * 16 + fr;
      bf_[kk] = *(const bf16x8*)(vtbase + (size_t)dhrow * Sc + it * 64 + kk * 32 + kg8);
    }
    {  // probs slab for this it (overlaps with MFMA below)
      ushort4 sv = *(const ushort4*)(S + prow * SWB + it * 64 + pc0);
      float4 e;
      e.x = bf2f(sv.x) * prv; e.y = bf2f(sv.y) * prv;
      e.z = bf2f(sv.z) * prv; e.w = bf2f(sv.w) * prv;
      *(float4*)(pbase + (size_t)prow * Sc + it * 64 + pc0) = e;
    }
#pragma unroll
    for (int kk = 0; kk < 2; ++kk) {
      bf16x8 afr = *(const bf16x8*)(S + fr * SWB + it * 64 + kk * 32 + kg8);
      pacc = __builtin_amdgcn_mfma_f32_16x16x32_bf16(afr, bf_[kk], pacc, 0, 0, 0);
    }
  }

  // ---- ctx epilogue ----
  float* cbase = ctx + (size_t)(b * Sc + q0) * Dc + h * DHc + w * 16;
#pragma unroll
  for (int r = 0; r < 4; ++r) {
    int row = fq * 4 + r;
    cbase[(size_t)row * Dc + fr] = pacc[r] * Rinv[row];
  }
}

extern "C" void kernel_launch(void* const* d_in, const int* in_sizes, int n_in,
                              void* d_out, int out_size, void* d_ws, size_t ws_size,
                              hipStream_t stream) {
  const float* hidden = (const float*)d_in[0];
  const float* amask = (const float*)d_in[1];
  const int* ind = (const int*)d_in[3];
  const int* outd = (const int*)d_in[4];
  const int* spe = (const int*)d_in[5];
  const float* Wq = (const float*)d_in[8];
  const float* bq = (const float*)d_in[9];
  const float* Wk = (const float*)d_in[10];
  const float* bk = (const float*)d_in[11];
  const float* Wv = (const float*)d_in[12];
  const float* bv = (const float*)d_in[13];
  const float* Win = (const float*)d_in[14];
  const float* Wout = (const float*)d_in[15];
  const float* Wspe = (const float*)d_in[16];

  char* ws = (char*)d_ws;
  const size_t BSD = (size_t)Bc * Sc * Dc;
  unsigned short* hbf = (unsigned short*)ws;                    // 16 MB
  unsigned short* Wtq = (unsigned short*)(ws + 16u * 1048576);  // 2 MB
  unsigned short* Wtk = (unsigned short*)(ws + 18u * 1048576);  // 2 MB
  unsigned short* Wtv = (unsigned short*)(ws + 20u * 1048576);  // 2 MB
  float* WspeT = (float*)(ws + 22u * 1048576);                  // 32 KB
  unsigned short* Qb = (unsigned short*)(ws + 24u * 1048576);   // 16 MB
  unsigned short* Kb = (unsigned short*)(ws + 40u * 1048576);   // 16 MB
  unsigned short* Vt = (unsigned short*)(ws + 56u * 1048576);   // 16 MB (transposed)
  float* ctx = (float*)d_out;
  float* probs = (float*)d_out + BSD;

  hipFuncSetAttribute((const void*)k_attn,
                      hipFuncAttributeMaxDynamicSharedMemorySize, 18752);

  k_pos_add<<<dim3(Bc * Sc), 256, 0, stream>>>(hidden, ind, outd, Win, Wout, hbf);
  k_wt<<<dim3(16, 16, 3), 256, 0, stream>>>(Wq, Wk, Wv, Wtq, Wtk, Wtv);
  k_wspet<<<dim3(32), 256, 0, stream>>>(Wspe, WspeT);
  k_gemm_mfma<<<dim3(8, 64, 3), 256, 0, stream>>>(hbf, Wtq, bq, Wtk, bk, Wtv, bv, Qb, Kb, Vt);
  k_attn<<<dim3(8192), 256, 18752, stream>>>(Qb, Kb, Vt, spe, WspeT, amask, probs, ctx);
}

// Round 10
// 242.591 us; speedup vs baseline: 1.6703x; 1.0818x over previous
//
#include <hip/hip_runtime.h>

#define Bc 16
#define Sc 512
#define Dc 1024
#define Hc 16
#define DHc 64

#define AS1 __attribute__((address_space(1)))
#define AS3 __attribute__((address_space(3)))

typedef __attribute__((ext_vector_type(8))) __bf16 bf16x8;
typedef __attribute__((ext_vector_type(4))) float f32x4;
typedef __attribute__((ext_vector_type(8))) unsigned short ushort8;

static __device__ __forceinline__ unsigned short f2bf(float f) {
  unsigned int u = __builtin_bit_cast(unsigned int, f);
  unsigned int r = (u + 0x7fffu + ((u >> 16) & 1u)) >> 16;  // RNE
  return (unsigned short)r;
}
static __device__ __forceinline__ float bf2f(unsigned short u) {
  unsigned int x = ((unsigned int)u) << 16;
  return __builtin_bit_cast(float, x);
}

// ---------------------------------------------------------------------------
// h_bf16 = bf16( hidden + (W_in*padmask)[in_degree] + (W_out*padmask)[out_degree] )
// ---------------------------------------------------------------------------
__global__ __launch_bounds__(256) void k_pos_add(
    const float* __restrict__ hidden, const int* __restrict__ ind,
    const int* __restrict__ outd, const float* __restrict__ Win,
    const float* __restrict__ Wout, unsigned short* __restrict__ hbf) {
  int row = blockIdx.x;
  int t = threadIdx.x;
  int id = ind[row], od = outd[row];
  float fi = (id != 0) ? 1.f : 0.f;
  float fo = (od != 0) ? 1.f : 0.f;
  float4 a = ((const float4*)(hidden + (size_t)row * Dc))[t];
  float4 x = ((const float4*)(Win + (size_t)id * Dc))[t];
  float4 y = ((const float4*)(Wout + (size_t)od * Dc))[t];
  ushort4 r;
  r.x = f2bf(a.x + fi * x.x + fo * y.x);
  r.y = f2bf(a.y + fi * x.y + fo * y.y);
  r.z = f2bf(a.z + fi * x.z + fo * y.z);
  r.w = f2bf(a.w + fi * x.w + fo * y.w);
  ((ushort4*)(hbf + (size_t)row * Dc))[t] = r;
}

// ---------------------------------------------------------------------------
// Wt[n][k] = bf16(W[k][n]) for q,k,v
// ---------------------------------------------------------------------------
__global__ __launch_bounds__(256) void k_wt(
    const float* __restrict__ Wq, const float* __restrict__ Wk,
    const float* __restrict__ Wv, unsigned short* __restrict__ Wtq,
    unsigned short* __restrict__ Wtk, unsigned short* __restrict__ Wtv) {
  const float* W = blockIdx.z == 0 ? Wq : blockIdx.z == 1 ? Wk : Wv;
  unsigned short* Wt = blockIdx.z == 0 ? Wtq : blockIdx.z == 1 ? Wtk : Wtv;
  __shared__ float tile[64][65];
  int k0 = blockIdx.y * 64, n0 = blockIdx.x * 64;
  int r = threadIdx.x >> 4, c4 = (threadIdx.x & 15) * 4;
  for (int rr = r; rr < 64; rr += 16) {
    float4 v = *(const float4*)(W + (size_t)(k0 + rr) * Dc + n0 + c4);
    tile[rr][c4 + 0] = v.x;
    tile[rr][c4 + 1] = v.y;
    tile[rr][c4 + 2] = v.z;
    tile[rr][c4 + 3] = v.w;
  }
  __syncthreads();
  for (int rr = r; rr < 64; rr += 16) {
    ushort4 o;
    o.x = f2bf(tile[c4 + 0][rr]);
    o.y = f2bf(tile[c4 + 1][rr]);
    o.z = f2bf(tile[c4 + 2][rr]);
    o.w = f2bf(tile[c4 + 3][rr]);
    *(ushort4*)(Wt + (size_t)(n0 + rr) * Dc + k0 + c4) = o;
  }
}

// ---------------------------------------------------------------------------
// WspeT[h][i] = Wspe[i][h]
// ---------------------------------------------------------------------------
__global__ __launch_bounds__(256) void k_wspet(
    const float* __restrict__ Wspe, float* __restrict__ WspeT) {
  int idx = blockIdx.x * 256 + threadIdx.x;  // 8192 total
  int h = idx >> 9, i = idx & 511;
  WspeT[idx] = Wspe[i * Hc + h];
}

// ---------------------------------------------------------------------------
// QKV projections, bf16 MFMA. Q pre-scaled by 1/8 (exact in bf16).
// Q,K row-major [b,s,1024]; V pre-transposed: Vt[(b*16+h), dh, s].
// ---------------------------------------------------------------------------
__global__ __launch_bounds__(256) void k_gemm_mfma(
    const unsigned short* __restrict__ hbf,
    const unsigned short* __restrict__ Wtq, const float* __restrict__ bq,
    const unsigned short* __restrict__ Wtk, const float* __restrict__ bk,
    const unsigned short* __restrict__ Wtv, const float* __restrict__ bv,
    unsigned short* __restrict__ Qo, unsigned short* __restrict__ Ko,
    unsigned short* __restrict__ Vt) {
  int zsel = blockIdx.z;
  const unsigned short* Wt;
  const float* bias;
  if (zsel == 0) { Wt = Wtq; bias = bq; }
  else if (zsel == 1) { Wt = Wtk; bias = bk; }
  else { Wt = Wtv; bias = bv; }

  __shared__ __align__(16) unsigned short As[128 * 32];
  __shared__ __align__(16) unsigned short Bs[128 * 32];

  int tid = threadIdx.x, lane = tid & 63, wave = tid >> 6;
  int m0 = blockIdx.y * 128, n0 = blockIdx.x * 128;
  int wr = wave >> 1, wc = wave & 1;

  f32x4 acc[4][4] = {};

  int srow = lane >> 2;
  int skb = (lane & 3) * 8;
  const unsigned short* gA = hbf + (size_t)(m0 + srow) * Dc + skb;
  const unsigned short* gB = Wt + (size_t)(n0 + srow) * Dc + skb;

  int fr = lane & 15, kg = (lane >> 4) * 8;

  for (int k0 = 0; k0 < Dc; k0 += 32) {
#pragma unroll
    for (int cc = 0; cc < 2; ++cc) {
      int c = wave + cc * 4;
      __builtin_amdgcn_global_load_lds(
          (const AS1 void*)(gA + (size_t)c * 16 * Dc + k0),
          (AS3 void*)(As + c * 16 * 32), 16, 0, 0);
      __builtin_amdgcn_global_load_lds(
          (const AS1 void*)(gB + (size_t)c * 16 * Dc + k0),
          (AS3 void*)(Bs + c * 16 * 32), 16, 0, 0);
    }
    __syncthreads();

    bf16x8 af[4], bfr[4];
#pragma unroll
    for (int m = 0; m < 4; ++m)
      af[m] = *(const bf16x8*)(As + (wr * 64 + m * 16 + fr) * 32 + kg);
#pragma unroll
    for (int n = 0; n < 4; ++n)
      bfr[n] = *(const bf16x8*)(Bs + (wc * 64 + n * 16 + fr) * 32 + kg);
#pragma unroll
    for (int m = 0; m < 4; ++m)
#pragma unroll
      for (int n = 0; n < 4; ++n)
        acc[m][n] = __builtin_amdgcn_mfma_f32_16x16x32_bf16(af[m], bfr[n], acc[m][n], 0, 0, 0);
    __syncthreads();
  }

  int fq = lane >> 4;
  if (zsel < 2) {
    unsigned short* C = (zsel == 0) ? Qo : Ko;
    float scale = (zsel == 0) ? 0.125f : 1.f;  // fold 1/sqrt(64) into Q (exact)
#pragma unroll
    for (int m = 0; m < 4; ++m) {
#pragma unroll
      for (int n = 0; n < 4; ++n) {
        int col = n0 + wc * 64 + n * 16 + fr;
        float bb = bias[col];
#pragma unroll
        for (int r = 0; r < 4; ++r) {
          int row = m0 + wr * 64 + m * 16 + fq * 4 + r;
          C[(size_t)row * Dc + col] = f2bf((acc[m][n][r] + bb) * scale);
        }
      }
    }
  } else {
#pragma unroll
    for (int m = 0; m < 4; ++m) {
#pragma unroll
      for (int n = 0; n < 4; ++n) {
        int col = n0 + wc * 64 + n * 16 + fr;
        int hh = col >> 6, dh = col & 63;
        float bb = bias[col];
        int row = m0 + wr * 64 + m * 16 + fq * 4;
        int bb_ = row >> 9, ss = row & 511;
        ushort4 pk;
        pk.x = f2bf(acc[m][n][0] + bb);
        pk.y = f2bf(acc[m][n][1] + bb);
        pk.z = f2bf(acc[m][n][2] + bb);
        pk.w = f2bf(acc[m][n][3] + bb);
        *(ushort4*)(Vt + ((size_t)(bb_ * Hc + hh) * DHc + dh) * Sc + ss) = pk;
      }
    }
  }
}

// ---------------------------------------------------------------------------
// Fused attention: block = (b, h, 16 q-rows); 4 waves; LDS 18752 B
// -> 8 blocks/CU. SWAPPED-operand MFMAs:
//   QK^T: mfma(K,Q) -> lane owns (q=fr, 4 contiguous k) -> ds_write_b64.
//   PV:   mfma(V^T,P) -> lane owns (q=fr, 4 contiguous dh) -> 16B ctx store.
// ---------------------------------------------------------------------------
#define SWB 520
__global__ __launch_bounds__(256, 8) void k_attn(
    const unsigned short* __restrict__ Qb, const unsigned short* __restrict__ Kb,
    const unsigned short* __restrict__ Vt, const int* __restrict__ spe,
    const float* __restrict__ WspeT, const float* __restrict__ mask,
    float* __restrict__ probs, float* __restrict__ ctx) {
  extern __shared__ char smem[];
  unsigned short* S = (unsigned short*)smem;     // 16*520*2 = 16640
  float* Wb = (float*)(smem + 16640);            // 2048
  float* Rinv = (float*)(smem + 16640 + 2048);   // 64

  int tid = threadIdx.x, lane = tid & 63, w = tid >> 6;
  int fr = lane & 15, fq = lane >> 4, kg8 = fq * 8;

  int flat = blockIdx.x;
  int swz = (flat & 7) * 1024 + (flat >> 3);
  int qt = swz & 31, h = (swz >> 5) & 15, b = swz >> 9;
  int q0 = qt * 16;

  // coalesced per-head bias row
  for (int i = tid; i < 512; i += 256) Wb[i] = WspeT[h * 512 + i];

  // Q fragments (pre-scaled by 1/8) in registers — B-operand of swapped QK^T
  const unsigned short* qbase = Qb + (size_t)(b * Sc + q0) * Dc + h * DHc;
  bf16x8 af[2];
#pragma unroll
  for (int kk = 0; kk < 2; ++kk)
    af[kk] = *(const bf16x8*)(qbase + (size_t)fr * Dc + kk * 32 + kg8);

  // ---- QK^T (swapped): acc = K-tile x Q -> D[k][q]; no barriers in loop ----
  const unsigned short* kbase = Kb + (size_t)(b * Sc) * Dc + h * DHc;
#pragma unroll 2
  for (int it = 0; it < 8; ++it) {
    bf16x8 kf[2];
#pragma unroll
    for (int kk = 0; kk < 2; ++kk) {
      int brow = it * 64 + w * 16 + fr;
      kf[kk] = *(const bf16x8*)(kbase + (size_t)brow * Dc + kk * 32 + kg8);
    }
    f32x4 acc = {};
#pragma unroll
    for (int kk = 0; kk < 2; ++kk)
      acc = __builtin_amdgcn_mfma_f32_16x16x32_bf16(kf[kk], af[kk], acc, 0, 0, 0);
    // lane: q-col = fr, k-rows = it*64 + w*16 + fq*4 + r (contiguous)
    ushort4 pk;
    pk.x = f2bf(acc[0]); pk.y = f2bf(acc[1]);
    pk.z = f2bf(acc[2]); pk.w = f2bf(acc[3]);
    *(ushort4*)(S + fr * SWB + it * 64 + w * 16 + fq * 4) = pk;
  }
  __syncthreads();  // barrier 1: S complete, Wb ready

  // ---- softmax: wave handles rows w*4..w*4+3; lane covers 8 contiguous cols ----
  {
    float4 mk0 = *(const float4*)(mask + b * Sc + lane * 8);
    float4 mk1 = *(const float4*)(mask + b * Sc + lane * 8 + 4);
#pragma unroll 2
    for (int r4 = 0; r4 < 4; ++r4) {
      int row = w * 4 + r4;
      unsigned short* sp = S + row * SWB + lane * 8;
      const int* spp = spe + (size_t)(b * Sc + q0 + row) * Sc + lane * 8;
      ushort8 sv = *(const ushort8*)sp;
      int4 i0 = *(const int4*)(spp);
      int4 i1 = *(const int4*)(spp + 4);
      float v0 = bf2f(sv[0]) + Wb[i0.x] + mk0.x;
      float v1 = bf2f(sv[1]) + Wb[i0.y] + mk0.y;
      float v2 = bf2f(sv[2]) + Wb[i0.z] + mk0.z;
      float v3 = bf2f(sv[3]) + Wb[i0.w] + mk0.w;
      float v4 = bf2f(sv[4]) + Wb[i1.x] + mk1.x;
      float v5 = bf2f(sv[5]) + Wb[i1.y] + mk1.y;
      float v6 = bf2f(sv[6]) + Wb[i1.z] + mk1.z;
      float v7 = bf2f(sv[7]) + Wb[i1.w] + mk1.w;
      float mx = fmaxf(fmaxf(fmaxf(v0, v1), fmaxf(v2, v3)),
                       fmaxf(fmaxf(v4, v5), fmaxf(v6, v7)));
#pragma unroll
      for (int o = 32; o; o >>= 1) mx = fmaxf(mx, __shfl_xor(mx, o));
      float e0 = __expf(v0 - mx), e1 = __expf(v1 - mx);
      float e2 = __expf(v2 - mx), e3 = __expf(v3 - mx);
      float e4 = __expf(v4 - mx), e5 = __expf(v5 - mx);
      float e6 = __expf(v6 - mx), e7 = __expf(v7 - mx);
      float sum = e0 + e1 + e2 + e3 + e4 + e5 + e6 + e7;
#pragma unroll
      for (int o = 32; o; o >>= 1) sum += __shfl_xor(sum, o);
      ushort8 ev;
      ev[0] = f2bf(e0); ev[1] = f2bf(e1); ev[2] = f2bf(e2); ev[3] = f2bf(e3);
      ev[4] = f2bf(e4); ev[5] = f2bf(e5); ev[6] = f2bf(e6); ev[7] = f2bf(e7);
      *(ushort8*)sp = ev;
      if (lane == 0) Rinv[row] = 1.f / sum;
    }
  }
  __syncthreads();  // barrier 2: exp(S) bf16, Rinv complete

  // ---- PV (swapped): pacc = V^T-tile x P -> D[dh][q]; + overlapped probs ----
  const unsigned short* vtbase = Vt + (size_t)(b * Hc + h) * DHc * Sc;
  float* pbase = probs + (size_t)((b * Hc + h) * Sc + q0) * Sc;
  int prow = tid >> 4, pc0 = (tid & 15) * 4;
  float prv = Rinv[prow];
  f32x4 pacc = {};
#pragma unroll 2
  for (int it = 0; it < 8; ++it) {
    bf16x8 vf[2];
#pragma unroll
    for (int kk = 0; kk < 2; ++kk) {
      int dhrow = w * 16 + fr;
      vf[kk] = *(const bf16x8*)(vtbase + (size_t)dhrow * Sc + it * 64 + kk * 32 + kg8);
    }
    {  // probs slab for this it (overlaps with MFMA below); NT store
      ushort4 sv = *(const ushort4*)(S + prow * SWB + it * 64 + pc0);
      f32x4 e;
      e[0] = bf2f(sv.x) * prv; e[1] = bf2f(sv.y) * prv;
      e[2] = bf2f(sv.z) * prv; e[3] = bf2f(sv.w) * prv;
      __builtin_nontemporal_store(e, (f32x4*)(pbase + (size_t)prow * Sc + it * 64 + pc0));
    }
#pragma unroll
    for (int kk = 0; kk < 2; ++kk) {
      bf16x8 pfr = *(const bf16x8*)(S + fr * SWB + it * 64 + kk * 32 + kg8);
      pacc = __builtin_amdgcn_mfma_f32_16x16x32_bf16(vf[kk], pfr, pacc, 0, 0, 0);
    }
  }

  // ---- ctx epilogue: lane = (q=fr, dh w*16+fq*4..+3) -> one 16B NT store ----
  {
    float rv = Rinv[fr];
    f32x4 o;
    o[0] = pacc[0] * rv; o[1] = pacc[1] * rv;
    o[2] = pacc[2] * rv; o[3] = pacc[3] * rv;
    __builtin_nontemporal_store(
        o, (f32x4*)(ctx + (size_t)(b * Sc + q0 + fr) * Dc + h * DHc + w * 16 + fq * 4));
  }
}

extern "C" void kernel_launch(void* const* d_in, const int* in_sizes, int n_in,
                              void* d_out, int out_size, void* d_ws, size_t ws_size,
                              hipStream_t stream) {
  const float* hidden = (const float*)d_in[0];
  const float* amask = (const float*)d_in[1];
  const int* ind = (const int*)d_in[3];
  const int* outd = (const int*)d_in[4];
  const int* spe = (const int*)d_in[5];
  const float* Wq = (const float*)d_in[8];
  const float* bq = (const float*)d_in[9];
  const float* Wk = (const float*)d_in[10];
  const float* bk = (const float*)d_in[11];
  const float* Wv = (const float*)d_in[12];
  const float* bv = (const float*)d_in[13];
  const float* Win = (const float*)d_in[14];
  const float* Wout = (const float*)d_in[15];
  const float* Wspe = (const float*)d_in[16];

  char* ws = (char*)d_ws;
  const size_t BSD = (size_t)Bc * Sc * Dc;
  unsigned short* hbf = (unsigned short*)ws;                    // 16 MB
  unsigned short* Wtq = (unsigned short*)(ws + 16u * 1048576);  // 2 MB
  unsigned short* Wtk = (unsigned short*)(ws + 18u * 1048576);  // 2 MB
  unsigned short* Wtv = (unsigned short*)(ws + 20u * 1048576);  // 2 MB
  float* WspeT = (float*)(ws + 22u * 1048576);                  // 32 KB
  unsigned short* Qb = (unsigned short*)(ws + 24u * 1048576);   // 16 MB
  unsigned short* Kb = (unsigned short*)(ws + 40u * 1048576);   // 16 MB
  unsigned short* Vt = (unsigned short*)(ws + 56u * 1048576);   // 16 MB (transposed)
  float* ctx = (float*)d_out;
  float* probs = (float*)d_out + BSD;

  (void)hipFuncSetAttribute((const void*)k_attn,
                            hipFuncAttributeMaxDynamicSharedMemorySize, 18752);

  k_pos_add<<<dim3(Bc * Sc), 256, 0, stream>>>(hidden, ind, outd, Win, Wout, hbf);
  k_wt<<<dim3(16, 16, 3), 256, 0, stream>>>(Wq, Wk, Wv, Wtq, Wtk, Wtv);
  k_wspet<<<dim3(32), 256, 0, stream>>>(Wspe, WspeT);
  k_gemm_mfma<<<dim3(8, 64, 3), 256, 0, stream>>>(hbf, Wtq, bq, Wtk, bk, Wtv, bv, Qb, Kb, Vt);
  k_attn<<<dim3(8192), 256, 18752, stream>>>(Qb, Kb, Vt, spe, WspeT, amask, probs, ctx);
}